// Round 10
// baseline (226.743 us; speedup 1.0000x reference)
//
#include <hip/hip_runtime.h>
#include <cstdint>

#define Bq 4
#define Lq 4096
#define Hq 256
#define NHq 8
#define Tq 64
#define WINq 16
#define Dq 32
#define NSLOTS 33
#define NEG_SLOPE 5.0f
#define MASK_FILL -1e12f
#define RPB 16         // rows per block for the two dense GEMMs (4 blocks/CU)
#define TLq 64         // l-tile for k_attn

__device__ __forceinline__ float leaky(float x) { return x >= 0.f ? x : NEG_SLOPE * x; }

__device__ __forceinline__ float4 fma4(float4 a, float s, float4 c) {
    float4 r;
    r.x = fmaf(a.x, s, c.x); r.y = fmaf(a.y, s, c.y);
    r.z = fmaf(a.z, s, c.z); r.w = fmaf(a.w, s, c.w);
    return r;
}

// ---------------- types projection + down_t + transposed copy ----------------
__global__ void k_types(const float* __restrict__ types, const float* __restrict__ Wt,
                        const float* __restrict__ bt, const float* __restrict__ down,
                        float* __restrict__ types_h, float* __restrict__ types_hT,
                        float* __restrict__ down_t) {
    int row = blockIdx.x;          // b*T + t
    int h = threadIdx.x;           // 0..255  (= n*32+d)
    int b = row >> 6, t = row & 63;
    __shared__ float in[Hq];
    __shared__ float outr[Hq];
    in[h] = types[(size_t)row * Hq + h];
    __syncthreads();
    float acc = bt[h];
    for (int k = 0; k < Hq; k += 4) {
        float4 iv = *(const float4*)&in[k];
        acc = fmaf(iv.x, Wt[(k + 0) * Hq + h], acc);
        acc = fmaf(iv.y, Wt[(k + 1) * Hq + h], acc);
        acc = fmaf(iv.z, Wt[(k + 2) * Hq + h], acc);
        acc = fmaf(iv.w, Wt[(k + 3) * Hq + h], acc);
    }
    types_h[(size_t)row * Hq + h] = acc;
    types_hT[(size_t)(b * Hq + h) * Tq + t] = acc;   // [b][n][d][t]
    outr[h] = acc;
    __syncthreads();
    if (h < NHq) {
        float s = 0.f;
        for (int d = 0; d < Dq; ++d) s += outr[h * Dq + d] * down[h * Dq + d];
        down_t[(b * NHq + h) * Tq + t] = s;
    }
}

// ---------------- context projection -> ctx_hT + upon_q / down_s ----------------
// 16 rows/block, thread = 4 rows × 4 cols  (1024 blocks → 4/CU latency hiding)
__global__ void __launch_bounds__(256) k_ctx(
        const float* __restrict__ ctx, const float* __restrict__ Wc,
        const float* __restrict__ bc, const float* __restrict__ upon,
        const float* __restrict__ down,
        float* __restrict__ ctx_hT, float* __restrict__ uq,
        float* __restrict__ dsv) {
    int row0 = blockIdx.x * RPB;
    int b = row0 >> 12, l0 = row0 & (Lq - 1);
    int tid = threadIdx.x;
    __shared__ float in[RPB][Hq];   // 16 KB
    {
        const float4* src = (const float4*)(ctx + (size_t)row0 * Hq);
        float4* dst = (float4*)(&in[0][0]);
#pragma unroll
        for (int j = 0; j < (RPB * Hq / 4) / 256; ++j)
            dst[tid + j * 256] = src[tid + j * 256];
    }
    __syncthreads();
    int c = tid & 63;              // float4 column group
    int rs = (tid >> 6) * 4;       // 4 rows (wave-uniform rs, LDS broadcast)
    const float4* W4 = (const float4*)Wc;
    float4 bv = ((const float4*)bc)[c];
    float4 acc[4];
#pragma unroll
    for (int j = 0; j < 4; ++j) acc[j] = bv;
    for (int k = 0; k < Hq; k += 4) {
        float4 w0 = W4[(k + 0) * 64 + c];
        float4 w1 = W4[(k + 1) * 64 + c];
        float4 w2 = W4[(k + 2) * 64 + c];
        float4 w3 = W4[(k + 3) * 64 + c];
#pragma unroll
        for (int j = 0; j < 4; ++j) {
            float4 iv = *(const float4*)&in[rs + j][k];
            acc[j] = fma4(w0, iv.x, acc[j]);
            acc[j] = fma4(w1, iv.y, acc[j]);
            acc[j] = fma4(w2, iv.z, acc[j]);
            acc[j] = fma4(w3, iv.w, acc[j]);
        }
    }
    __syncthreads();               // raw `in` no longer needed
#pragma unroll
    for (int j = 0; j < 4; ++j)
        ((float4*)&in[rs + j][0])[c] = acc[j];
    __syncthreads();
    // uq / dsv : threads 0..127 -> (r, n)
    if (tid < RPB * NHq) {
        int r = tid >> 3, n = tid & 7;
        float su = 0.f, sd = 0.f;
        for (int d = 0; d < Dq; ++d) {
            float v = in[r][n * Dq + d];
            su += v * upon[n * Dq + d];
            sd += v * down[n * Dq + d];
        }
        uq[(b * NHq + n) * Lq + l0 + r] = su;
        dsv[(b * NHq + n) * Lq + l0 + r] = sd;
    }
    // transposed store: thread tid owns channel tid, writes 16 l's (64 B)
    {
        float* dst = ctx_hT + (size_t)(b * Hq + tid) * Lq + l0;
#pragma unroll
        for (int j = 0; j < RPB / 4; ++j) {
            float4 o;
            o.x = in[4 * j + 0][tid];
            o.y = in[4 * j + 1][tid];
            o.z = in[4 * j + 2][tid];
            o.w = in[4 * j + 3][tid];
            ((float4*)dst)[j] = o;
        }
    }
}

// ---------------- attention: tiled (b, n, 64 l's) per block ----------------
__global__ void __launch_bounds__(256) k_attn(
        const float* __restrict__ ctx_hT, const float* __restrict__ types_h,
        const float* __restrict__ types_hT, const float* __restrict__ cross,
        const float* __restrict__ uq, const float* __restrict__ dsv,
        const float* __restrict__ dt, const unsigned char* __restrict__ maskp,
        float* __restrict__ update) {
    int blk = blockIdx.x;
    int lt = blk & 63, n = (blk >> 6) & 7, b = blk >> 9;
    int l0 = lt * TLq;
    int tid = threadIdx.x;
    int ls = tid >> 2;             // l_sub 0..63
    int q  = tid & 3;              // quad lane
    int pl = l0 + ls;              // global l
    bool mask_b8 = (maskp[1] != 0);

    __shared__ float chx_s[32 * 97];        // [d][le] extended window
    __shared__ float crs_s[32 * 36];        // cross[n] [d][i]
    __shared__ float cr_s[64 * 36];         // cr [l][i]
    __shared__ float dots_s[64 * 19];       // [l][u], u=1..16 used
    __shared__ float tts_s[32 * 64];        // types tile [d][t]  (phase 4)
    __shared__ float tts2_s[64 * 36 + 16];  // types tile [t][d], swizzled (phase 6)
    __shared__ float uqe[96], dsve[96], maskf[96], dts[64];

    // ---- phase 1: staging ----
    {
        int d = tid >> 3, k = tid & 7;
        const float* grow = ctx_hT + ((size_t)(b * NHq + n) * Dq + d) * Lq;
        float* lrow = &chx_s[d * 97 + k * 12];
        if (l0 >= 16 && l0 <= Lq - 80) {
            const float4* g = (const float4*)(grow + (l0 - 16) + k * 12);
            float4 v0 = g[0], v1 = g[1], v2 = g[2];
            lrow[0] = v0.x; lrow[1] = v0.y; lrow[2]  = v0.z; lrow[3]  = v0.w;
            lrow[4] = v1.x; lrow[5] = v1.y; lrow[6]  = v1.z; lrow[7]  = v1.w;
            lrow[8] = v2.x; lrow[9] = v2.y; lrow[10] = v2.z; lrow[11] = v2.w;
        } else {
#pragma unroll
            for (int m = 0; m < 12; ++m) {
                int gl = l0 - 16 + k * 12 + m;
                int glw = (gl < 0) ? gl + Lq : ((gl >= Lq) ? gl - Lq : gl);
                lrow[m] = grow[glw];
            }
        }
    }
    {   // cross[n]: 1024 floats, 4 per thread
        float4 v = ((const float4*)(cross + n * (Dq * Dq)))[tid];
        float* p = &crs_s[(tid >> 3) * 36 + (tid & 7) * 4];
        p[0] = v.x; p[1] = v.y; p[2] = v.z; p[3] = v.w;
    }
    {   // tts_s [d][t] from types_hT (contiguous)
        const float4* src = (const float4*)(types_hT + (size_t)(b * NHq + n) * Dq * Tq);
        float4* dst = (float4*)tts_s;
        dst[tid] = src[tid];
        dst[tid + 256] = src[tid + 256];
    }
    {   // tts2_s [t][d] from types_h rows; swizzled row base t*36 + 4*(t>>4)
        int t = tid >> 2, c4 = tid & 3;
        const float4* src = (const float4*)(types_h + (size_t)(b * Tq + t) * Hq
                                            + n * Dq + 8 * c4);
        float* p = &tts2_s[t * 36 + 4 * (t >> 4) + 8 * c4];
        ((float4*)p)[0] = src[0];
        ((float4*)p)[1] = src[1];
    }
    if (tid < 96) {
        int gl = l0 - 16 + tid;
        int glw = (gl < 0) ? gl + Lq : ((gl >= Lq) ? gl - Lq : gl);
        uqe[tid] = uq[(b * NHq + n) * Lq + glw];
        unsigned char mb = mask_b8 ? maskp[b * Lq + glw]
                                   : maskp[(size_t)(b * Lq + glw) * 4];
        maskf[tid] = mb ? 1.f : 0.f;
    } else if (tid < 192) {
        int j = tid - 96;
        int gl = l0 - 16 + j;
        int glw = (gl < 0) ? gl + Lq : ((gl >= Lq) ? gl - Lq : gl);
        dsve[j] = dsv[(b * NHq + n) * Lq + glw];
    } else {
        dts[tid - 192] = dt[(b * NHq + n) * Tq + (tid - 192)];
    }
    __syncthreads();   // the ONLY barrier: everything below is intra-wave

    // ---- phase 2: cr[l][i] = sum_d chx[d][center] * cross[d][i]; i = 8q+ii ----
    {
        float a[8];
#pragma unroll
        for (int ii = 0; ii < 8; ++ii) a[ii] = 0.f;
#pragma unroll 2
        for (int d = 0; d < Dq; ++d) {
            float chv = chx_s[d * 97 + ls + 16];
            const float4* cp = (const float4*)(&crs_s[d * 36 + 8 * q]);
            float4 c0 = cp[0], c1 = cp[1];
            a[0] = fmaf(chv, c0.x, a[0]); a[1] = fmaf(chv, c0.y, a[1]);
            a[2] = fmaf(chv, c0.z, a[2]); a[3] = fmaf(chv, c0.w, a[3]);
            a[4] = fmaf(chv, c1.x, a[4]); a[5] = fmaf(chv, c1.y, a[5]);
            a[6] = fmaf(chv, c1.z, a[6]); a[7] = fmaf(chv, c1.w, a[7]);
        }
        // quad ls writes row ls; only quad ls reads it later (same wave)
        float4* wp = (float4*)(&cr_s[ls * 36 + 8 * q]);
        wp[0] = make_float4(a[0], a[1], a[2], a[3]);
        wp[1] = make_float4(a[4], a[5], a[6], a[7]);
    }

    // ---- phase 3: window dots, quad-split over d (lane q owns d=8q..8q+7) ----
    float dot_self;
    {
        float cv8[8];
#pragma unroll
        for (int k = 0; k < 8; ++k) cv8[k] = cr_s[ls * 36 + 8 * q + k];
#pragma unroll
        for (int u = 0; u < 17; ++u) {
            float a = 0.f;
#pragma unroll
            for (int k = 0; k < 8; ++k)
                a = fmaf(cv8[k], chx_s[(8 * q + k) * 97 + ls + 16 + u], a);
            a += __shfl_xor(a, 1);
            a += __shfl_xor(a, 2);
            if (u == 0) dot_self = a;
            else if (q == 0) dots_s[ls * 19 + u] = a;   // intra-wave producer
        }
    }

    float uq_l = uqe[ls + 16];
    float dsv_l = dsve[ls + 16];
    float cmask = maskf[ls + 16];

    // ---- phase 4a: type logits, t = tb..tb+15; cv streamed from LDS ----
    int tb = 16 * q;
    float st[16];
#pragma unroll
    for (int j = 0; j < 16; ++j) st[j] = 0.f;
#pragma unroll 2
    for (int d = 0; d < Dq; ++d) {
        float cv = cr_s[ls * 36 + d];
        const float4* r4 = (const float4*)&tts_s[d * 64 + tb];
        float4 r0 = r4[0], r1 = r4[1], r2 = r4[2], r3 = r4[3];
        st[0]  = fmaf(cv, r0.x, st[0]);  st[1]  = fmaf(cv, r0.y, st[1]);
        st[2]  = fmaf(cv, r0.z, st[2]);  st[3]  = fmaf(cv, r0.w, st[3]);
        st[4]  = fmaf(cv, r1.x, st[4]);  st[5]  = fmaf(cv, r1.y, st[5]);
        st[6]  = fmaf(cv, r1.z, st[6]);  st[7]  = fmaf(cv, r1.w, st[7]);
        st[8]  = fmaf(cv, r2.x, st[8]);  st[9]  = fmaf(cv, r2.y, st[9]);
        st[10] = fmaf(cv, r2.z, st[10]); st[11] = fmaf(cv, r2.w, st[11]);
        st[12] = fmaf(cv, r3.x, st[12]); st[13] = fmaf(cv, r3.y, st[13]);
        st[14] = fmaf(cv, r3.z, st[14]); st[15] = fmaf(cv, r3.w, st[15]);
    }
#pragma unroll
    for (int j = 0; j < 16; ++j)
        st[j] = leaky(uq_l + dts[tb + j] + st[j]);

    // ---- phase 4b: upper window logits (u = q+1+4j; dots via intra-wave LDS) ----
    int nv = (q == 0) ? 5 : 4;
    float su[4];
#pragma unroll
    for (int j = 0; j < 4; ++j) {
        int u = q + 1 + 4 * j;
        bool ok = (pl + u < Lq) && (maskf[ls + 16 + u] > 0.5f);
        su[j] = ok ? leaky(uqe[ls + 16 + u] + dsv_l + dots_s[ls * 19 + u])
                   : MASK_FILL;
    }

    // ---- phase 5: softmax over the quad's 97 logits ----
    float m = st[0];
#pragma unroll
    for (int j = 1; j < 16; ++j) m = fmaxf(m, st[j]);
#pragma unroll
    for (int j = 0; j < 5; ++j) {   // lower slots: compute on the fly for max
        if (j < nv) {
            int v = q + 4 * j;
            if ((pl + v >= 16) && (cmask > 0.5f))
                m = fmaxf(m, leaky(uq_l + dsve[ls + v] + dot_self));
        }
    }
#pragma unroll
    for (int j = 0; j < 4; ++j) m = fmaxf(m, su[j]);
    m = fmaxf(m, __shfl_xor(m, 1));
    m = fmaxf(m, __shfl_xor(m, 2));
    float sum = 0.f, wself = 0.f;
#pragma unroll
    for (int j = 0; j < 16; ++j) { st[j] = __expf(st[j] - m); sum += st[j]; }
#pragma unroll
    for (int j = 0; j < 5; ++j) {   // recompute lower slots, fold into wself
        if (j < nv) {
            int v = q + 4 * j;
            if ((pl + v >= 16) && (cmask > 0.5f)) {
                float e = __expf(leaky(uq_l + dsve[ls + v] + dot_self) - m);
                wself += e; sum += e;
            }
        }
    }
#pragma unroll
    for (int j = 0; j < 4; ++j)  { su[j] = __expf(su[j] - m); sum += su[j]; }
    sum += __shfl_xor(sum, 1);
    sum += __shfl_xor(sum, 2);
    float inv = 1.f / sum;
#pragma unroll
    for (int j = 0; j < 16; ++j) st[j] *= inv;
    wself *= inv;
#pragma unroll
    for (int j = 0; j < 4; ++j)  su[j] *= inv;

    // ---- phase 6: update, d-chunked (8 at a time); values from LDS ----
    float* dstrow = update + (size_t)(b * Lq + pl) * Hq + n * Dq;
#pragma unroll
    for (int c = 0; c < 4; ++c) {
        float u8[8];
#pragma unroll
        for (int e = 0; e < 8; ++e) u8[e] = 0.f;
#pragma unroll 2
        for (int j = 0; j < 16; ++j) {
            const float* vp = &tts2_s[(tb + j) * 36 + 4 * q + 8 * c];
            float4 a0 = ((const float4*)vp)[0];
            float4 a1 = ((const float4*)vp)[1];
            float wt = st[j];
            u8[0] = fmaf(wt, a0.x, u8[0]); u8[1] = fmaf(wt, a0.y, u8[1]);
            u8[2] = fmaf(wt, a0.z, u8[2]); u8[3] = fmaf(wt, a0.w, u8[3]);
            u8[4] = fmaf(wt, a1.x, u8[4]); u8[5] = fmaf(wt, a1.y, u8[5]);
            u8[6] = fmaf(wt, a1.z, u8[6]); u8[7] = fmaf(wt, a1.w, u8[7]);
        }
#pragma unroll
        for (int e = 0; e < 8; ++e)
            u8[e] = fmaf(wself, chx_s[(8 * c + e) * 97 + ls + 16], u8[e]);
#pragma unroll
        for (int j = 0; j < 4; ++j) {
            float wu = su[j];
            int u = q + 1 + 4 * j;
#pragma unroll
            for (int e = 0; e < 8; ++e)
                u8[e] = fmaf(wu, chx_s[(8 * c + e) * 97 + ls + 16 + u], u8[e]);
        }
#pragma unroll
        for (int e = 0; e < 8; ++e) {
            u8[e] += __shfl_xor(u8[e], 1);
            u8[e] += __shfl_xor(u8[e], 2);
        }
        if (q == c) {
            ((float4*)(dstrow + 8 * c))[0] = make_float4(u8[0], u8[1], u8[2], u8[3]);
            ((float4*)(dstrow + 8 * c))[1] = make_float4(u8[4], u8[5], u8[6], u8[7]);
        }
    }
}

// ---------------- output GEMM + tanh ----------------
// 16 rows/block, thread = 4 rows × 4 cols; stores direct from registers
__global__ void __launch_bounds__(256) k_out(
        const float* __restrict__ update, const float* __restrict__ ctx,
        const float* __restrict__ Wo, const float* __restrict__ bo,
        float* __restrict__ out) {
    int row0 = blockIdx.x * RPB;
    int tid = threadIdx.x;
    __shared__ float in[RPB][Hq];
    {
        const float4* s0 = (const float4*)(update + (size_t)row0 * Hq);
        const float4* s1 = (const float4*)(ctx + (size_t)row0 * Hq);
        float4* dst = (float4*)(&in[0][0]);
#pragma unroll
        for (int j = 0; j < (RPB * Hq / 4) / 256; ++j) {
            float4 a = s0[tid + j * 256], bvv = s1[tid + j * 256];
            float4 r; r.x = a.x + bvv.x; r.y = a.y + bvv.y;
            r.z = a.z + bvv.z; r.w = a.w + bvv.w;
            dst[tid + j * 256] = r;
        }
    }
    __syncthreads();
    int c = tid & 63;
    int rs = (tid >> 6) * 4;
    const float4* W4 = (const float4*)Wo;
    float4 bv = ((const float4*)bo)[c];
    float4 acc[4];
#pragma unroll
    for (int j = 0; j < 4; ++j) acc[j] = bv;
    for (int k = 0; k < Hq; k += 4) {
        float4 w0 = W4[(k + 0) * 64 + c];
        float4 w1 = W4[(k + 1) * 64 + c];
        float4 w2 = W4[(k + 2) * 64 + c];
        float4 w3 = W4[(k + 3) * 64 + c];
#pragma unroll
        for (int j = 0; j < 4; ++j) {
            float4 iv = *(const float4*)&in[rs + j][k];
            acc[j] = fma4(w0, iv.x, acc[j]);
            acc[j] = fma4(w1, iv.y, acc[j]);
            acc[j] = fma4(w2, iv.z, acc[j]);
            acc[j] = fma4(w3, iv.w, acc[j]);
        }
    }
#pragma unroll
    for (int j = 0; j < 4; ++j) {
        float4 o;
        o.x = tanhf(acc[j].x); o.y = tanhf(acc[j].y);
        o.z = tanhf(acc[j].z); o.w = tanhf(acc[j].w);
        ((float4*)(out + (size_t)(row0 + rs + j) * Hq))[c] = o;
    }
}

extern "C" void kernel_launch(void* const* d_in, const int* in_sizes, int n_in,
                              void* d_out, int out_size, void* d_ws, size_t ws_size,
                              hipStream_t stream) {
    const float* context   = (const float*)d_in[0];
    const float* types     = (const float*)d_in[1];
    const unsigned char* cmask = (const unsigned char*)d_in[2];
    const float* W_types   = (const float*)d_in[3];
    const float* b_types   = (const float*)d_in[4];
    const float* W_context = (const float*)d_in[5];
    const float* b_context = (const float*)d_in[6];
    const float* upon      = (const float*)d_in[7];
    const float* down      = (const float*)d_in[8];
    const float* cross     = (const float*)d_in[9];
    const float* W_out     = (const float*)d_in[10];
    const float* b_out     = (const float*)d_in[11];
    float* out = (float*)d_out;
    float* ws  = (float*)d_ws;

    // ws: only the two 16MB tensors (32 MiB total — proven-safe size).
    float* ctx_hT   = ws;             // [b][n][d][l]
    float* update   = ws + 4194304;

    // Small intermediates in d_out scratch (k_out overwrites all of d_out last).
    float* types_h  = out;            // 65536   [b][t][h]
    float* types_hT = out + 65536;    // 65536   [b][n][d][t]
    float* down_t   = out + 131072;   // 2048
    float* uqp      = out + 133120;   // 131072
    float* dsvp     = out + 264192;   // 131072

    k_types<<<Bq * Tq, Hq, 0, stream>>>(types, W_types, b_types, down,
                                        types_h, types_hT, down_t);
    k_ctx<<<Bq * Lq / RPB, 256, 0, stream>>>(context, W_context, b_context, upon, down,
                                             ctx_hT, uqp, dsvp);
    k_attn<<<Bq * NHq * (Lq / TLq), 256, 0, stream>>>(ctx_hT, types_h, types_hT, cross,
                                                      uqp, dsvp, down_t, cmask, update);
    k_out<<<Bq * Lq / RPB, 256, 0, stream>>>(update, context, W_out, b_out, out);
}

// Round 11
// 205.446 us; speedup vs baseline: 1.1037x; 1.1037x over previous
//
#include <hip/hip_runtime.h>
#include <cstdint>

#define Bq 4
#define Lq 4096
#define Hq 256
#define NHq 8
#define Tq 64
#define WINq 16
#define Dq 32
#define NSLOTS 33
#define NEG_SLOPE 5.0f
#define MASK_FILL -1e12f
#define TLq 64         // l-tile for k_attn
#define MB 32          // rows per block for MFMA GEMMs

typedef __attribute__((ext_vector_type(8))) short short8;
typedef __attribute__((ext_vector_type(4))) float f32x4;

__device__ __forceinline__ float leaky(float x) { return x >= 0.f ? x : NEG_SLOPE * x; }

__device__ __forceinline__ uint16_t f2bf(float x) {   // RNE f32->bf16 bits
    uint32_t u = __float_as_uint(x);
    uint32_t r = (u + 0x7fffu + ((u >> 16) & 1u)) >> 16;
    return (uint16_t)r;
}
__device__ __forceinline__ float bf2f(uint16_t h) {
    return __uint_as_float(((uint32_t)h) << 16);
}

// ---------------- W packing: MFMA B-fragment order, hi/lo bf16 ----------------
// dst[fragi*512 + l*8 + j] = W[kc*32 + (l>>4)*8 + j][nt*16 + (l&15)], fragi = nt*8+kc
__global__ void k_wprep(const float* __restrict__ Wc, const float* __restrict__ Wo,
                        uint16_t* __restrict__ pc_hi, uint16_t* __restrict__ pc_lo,
                        uint16_t* __restrict__ po_hi, uint16_t* __restrict__ po_lo) {
    int wsel = blockIdx.x >> 6;
    int blk = blockIdx.x & 63;
    const float* W = wsel ? Wo : Wc;
    uint16_t* ph = wsel ? po_hi : pc_hi;
    uint16_t* pl = wsel ? po_lo : pc_lo;
    int base = blk * 1024;
    for (int idx = base + threadIdx.x; idx < base + 1024; idx += 256) {
        int j = idx & 7, l = (idx >> 3) & 63, fragi = idx >> 9;
        int kc = fragi & 7, nt = fragi >> 3;
        int k = kc * 32 + (l >> 4) * 8 + j;
        int c = nt * 16 + (l & 15);
        float x = W[k * Hq + c];
        uint16_t h = f2bf(x);
        ph[idx] = h;
        pl[idx] = f2bf(x - bf2f(h));
    }
}

// ---------------- types projection + down_t + transposed copy ----------------
__global__ void k_types(const float* __restrict__ types, const float* __restrict__ Wt,
                        const float* __restrict__ bt, const float* __restrict__ down,
                        float* __restrict__ types_h, float* __restrict__ types_hT,
                        float* __restrict__ down_t) {
    int row = blockIdx.x;          // b*T + t
    int h = threadIdx.x;
    int b = row >> 6, t = row & 63;
    __shared__ float in[Hq];
    __shared__ float outr[Hq];
    in[h] = types[(size_t)row * Hq + h];
    __syncthreads();
    float acc = bt[h];
    for (int k = 0; k < Hq; k += 4) {
        float4 iv = *(const float4*)&in[k];
        acc = fmaf(iv.x, Wt[(k + 0) * Hq + h], acc);
        acc = fmaf(iv.y, Wt[(k + 1) * Hq + h], acc);
        acc = fmaf(iv.z, Wt[(k + 2) * Hq + h], acc);
        acc = fmaf(iv.w, Wt[(k + 3) * Hq + h], acc);
    }
    types_h[(size_t)row * Hq + h] = acc;
    types_hT[(size_t)(b * Hq + h) * Tq + t] = acc;   // [b][n][d][t]
    outr[h] = acc;
    __syncthreads();
    if (h < NHq) {
        float s = 0.f;
        for (int d = 0; d < Dq; ++d) s += outr[h * Dq + d] * down[h * Dq + d];
        down_t[(b * NHq + h) * Tq + t] = s;
    }
}

// ---------------- context projection via MFMA (bf16 hi/lo split) ----------------
#define APAD 264       // bf16 row stride for A tiles (16B-aligned, bank-staggered)
#define OPAD 258       // f32 row stride for output staging
__global__ void __launch_bounds__(256) k_ctx(
        const float* __restrict__ ctx,
        const uint16_t* __restrict__ wp_hi, const uint16_t* __restrict__ wp_lo,
        const float* __restrict__ bc, const float* __restrict__ upon,
        const float* __restrict__ down,
        float* __restrict__ ctx_hT, float* __restrict__ uq,
        float* __restrict__ dsv) {
    int row0 = blockIdx.x * MB;
    int b = row0 >> 12, l0 = row0 & (Lq - 1);
    int tid = threadIdx.x;
    int w = tid >> 6, l = tid & 63;
    __shared__ __align__(16) char smem_raw[33792];
    uint16_t* a_hi = (uint16_t*)smem_raw;            // [32][APAD]
    uint16_t* a_lo = a_hi + MB * APAD;
    float* outb = (float*)smem_raw;                  // reused: [32][OPAD]

    // stage + split rows
    {
        const float4* src = (const float4*)(ctx + (size_t)row0 * Hq);
#pragma unroll
        for (int j = 0; j < 8; ++j) {
            int f = tid + j * 256;
            int r = f >> 6, cg = f & 63;
            float4 v = src[f];
            uint16_t h0 = f2bf(v.x), h1 = f2bf(v.y), h2 = f2bf(v.z), h3 = f2bf(v.w);
            ushort4 hh = {h0, h1, h2, h3};
            ushort4 ll = {f2bf(v.x - bf2f(h0)), f2bf(v.y - bf2f(h1)),
                          f2bf(v.z - bf2f(h2)), f2bf(v.w - bf2f(h3))};
            *(ushort4*)&a_hi[r * APAD + cg * 4] = hh;
            *(ushort4*)&a_lo[r * APAD + cg * 4] = ll;
        }
    }
    __syncthreads();

    int wr = (w >> 1) * 16;        // wave row base (0 or 16)
    int nt0 = (w & 1) * 8;         // wave col-tile base
    int m = l & 15, quad = l >> 4;
    f32x4 acc[8];
#pragma unroll
    for (int t = 0; t < 8; ++t) acc[t] = (f32x4){0.f, 0.f, 0.f, 0.f};
    for (int kc = 0; kc < 8; ++kc) {
        short8 ah = *(const short8*)&a_hi[(wr + m) * APAD + kc * 32 + quad * 8];
        short8 al = *(const short8*)&a_lo[(wr + m) * APAD + kc * 32 + quad * 8];
#pragma unroll
        for (int t = 0; t < 8; ++t) {
            int fragi = (nt0 + t) * 8 + kc;
            short8 wh = *(const short8*)&wp_hi[fragi * 512 + l * 8];
            short8 wl = *(const short8*)&wp_lo[fragi * 512 + l * 8];
            acc[t] = __builtin_amdgcn_mfma_f32_16x16x32_bf16(ah, wh, acc[t], 0, 0, 0);
            acc[t] = __builtin_amdgcn_mfma_f32_16x16x32_bf16(ah, wl, acc[t], 0, 0, 0);
            acc[t] = __builtin_amdgcn_mfma_f32_16x16x32_bf16(al, wh, acc[t], 0, 0, 0);
        }
    }
    __syncthreads();   // all a_hi/a_lo reads done; reuse smem as outb

    // write C (+bias) to LDS staging
#pragma unroll
    for (int t = 0; t < 8; ++t) {
        int col = (nt0 + t) * 16 + m;
        float bv = bc[col];
#pragma unroll
        for (int r = 0; r < 4; ++r)
            outb[(wr + quad * 4 + r) * OPAD + col] = acc[t][r] + bv;
    }
    __syncthreads();

    // uq / dsv: one (r,n) pair per thread
    {
        int r = tid >> 3, n = tid & 7;
        float su = 0.f, sd = 0.f;
        for (int d = 0; d < Dq; ++d) {
            float v = outb[r * OPAD + n * Dq + d];
            su += v * upon[n * Dq + d];
            sd += v * down[n * Dq + d];
        }
        uq[(b * NHq + n) * Lq + l0 + r] = su;
        dsv[(b * NHq + n) * Lq + l0 + r] = sd;
    }
    // transposed store: thread tid owns channel tid, writes 32 l's
    {
        float* dst = ctx_hT + (size_t)(b * Hq + tid) * Lq + l0;
#pragma unroll
        for (int j = 0; j < MB / 4; ++j) {
            float4 o;
            o.x = outb[(4 * j + 0) * OPAD + tid];
            o.y = outb[(4 * j + 1) * OPAD + tid];
            o.z = outb[(4 * j + 2) * OPAD + tid];
            o.w = outb[(4 * j + 3) * OPAD + tid];
            ((float4*)dst)[j] = o;
        }
    }
}

// ---------------- attention: tiled (b, n, 64 l's) per block (unchanged R9) ----
__global__ void __launch_bounds__(256) k_attn(
        const float* __restrict__ ctx_hT, const float* __restrict__ types_h,
        const float* __restrict__ types_hT, const float* __restrict__ cross,
        const float* __restrict__ uq, const float* __restrict__ dsv,
        const float* __restrict__ dt, const unsigned char* __restrict__ maskp,
        float* __restrict__ update) {
    int blk = blockIdx.x;
    int lt = blk & 63, n = (blk >> 6) & 7, b = blk >> 9;
    int l0 = lt * TLq;
    int tid = threadIdx.x;
    int ls = tid >> 2;
    int q  = tid & 3;
    int pl = l0 + ls;
    bool mask_b8 = (maskp[1] != 0);

    __shared__ float chx_s[32 * 97];
    __shared__ float crs_s[32 * 36];
    __shared__ float cr_s[64 * 36];
    __shared__ float dots_s[64 * 19];
    __shared__ float tts_s[32 * 64];
    __shared__ float tts2_s[64 * 36 + 16];
    __shared__ float uqe[96], dsve[96], maskf[96], dts[64];

    {
        int d = tid >> 3, k = tid & 7;
        const float* grow = ctx_hT + ((size_t)(b * NHq + n) * Dq + d) * Lq;
        float* lrow = &chx_s[d * 97 + k * 12];
        if (l0 >= 16 && l0 <= Lq - 80) {
            const float4* g = (const float4*)(grow + (l0 - 16) + k * 12);
            float4 v0 = g[0], v1 = g[1], v2 = g[2];
            lrow[0] = v0.x; lrow[1] = v0.y; lrow[2]  = v0.z; lrow[3]  = v0.w;
            lrow[4] = v1.x; lrow[5] = v1.y; lrow[6]  = v1.z; lrow[7]  = v1.w;
            lrow[8] = v2.x; lrow[9] = v2.y; lrow[10] = v2.z; lrow[11] = v2.w;
        } else {
#pragma unroll
            for (int m = 0; m < 12; ++m) {
                int gl = l0 - 16 + k * 12 + m;
                int glw = (gl < 0) ? gl + Lq : ((gl >= Lq) ? gl - Lq : gl);
                lrow[m] = grow[glw];
            }
        }
    }
    {
        float4 v = ((const float4*)(cross + n * (Dq * Dq)))[tid];
        float* p = &crs_s[(tid >> 3) * 36 + (tid & 7) * 4];
        p[0] = v.x; p[1] = v.y; p[2] = v.z; p[3] = v.w;
    }
    {
        const float4* src = (const float4*)(types_hT + (size_t)(b * NHq + n) * Dq * Tq);
        float4* dst = (float4*)tts_s;
        dst[tid] = src[tid];
        dst[tid + 256] = src[tid + 256];
    }
    {
        int t = tid >> 2, c4 = tid & 3;
        const float4* src = (const float4*)(types_h + (size_t)(b * Tq + t) * Hq
                                            + n * Dq + 8 * c4);
        float* p = &tts2_s[t * 36 + 4 * (t >> 4) + 8 * c4];
        ((float4*)p)[0] = src[0];
        ((float4*)p)[1] = src[1];
    }
    if (tid < 96) {
        int gl = l0 - 16 + tid;
        int glw = (gl < 0) ? gl + Lq : ((gl >= Lq) ? gl - Lq : gl);
        uqe[tid] = uq[(b * NHq + n) * Lq + glw];
        unsigned char mb = mask_b8 ? maskp[b * Lq + glw]
                                   : maskp[(size_t)(b * Lq + glw) * 4];
        maskf[tid] = mb ? 1.f : 0.f;
    } else if (tid < 192) {
        int j = tid - 96;
        int gl = l0 - 16 + j;
        int glw = (gl < 0) ? gl + Lq : ((gl >= Lq) ? gl - Lq : gl);
        dsve[j] = dsv[(b * NHq + n) * Lq + glw];
    } else {
        dts[tid - 192] = dt[(b * NHq + n) * Tq + (tid - 192)];
    }
    __syncthreads();

    {
        float a[8];
#pragma unroll
        for (int ii = 0; ii < 8; ++ii) a[ii] = 0.f;
#pragma unroll 2
        for (int d = 0; d < Dq; ++d) {
            float chv = chx_s[d * 97 + ls + 16];
            const float4* cp = (const float4*)(&crs_s[d * 36 + 8 * q]);
            float4 c0 = cp[0], c1 = cp[1];
            a[0] = fmaf(chv, c0.x, a[0]); a[1] = fmaf(chv, c0.y, a[1]);
            a[2] = fmaf(chv, c0.z, a[2]); a[3] = fmaf(chv, c0.w, a[3]);
            a[4] = fmaf(chv, c1.x, a[4]); a[5] = fmaf(chv, c1.y, a[5]);
            a[6] = fmaf(chv, c1.z, a[6]); a[7] = fmaf(chv, c1.w, a[7]);
        }
        float4* wp = (float4*)(&cr_s[ls * 36 + 8 * q]);
        wp[0] = make_float4(a[0], a[1], a[2], a[3]);
        wp[1] = make_float4(a[4], a[5], a[6], a[7]);
    }

    float dot_self;
    {
        float cv8[8];
#pragma unroll
        for (int k = 0; k < 8; ++k) cv8[k] = cr_s[ls * 36 + 8 * q + k];
#pragma unroll
        for (int u = 0; u < 17; ++u) {
            float a = 0.f;
#pragma unroll
            for (int k = 0; k < 8; ++k)
                a = fmaf(cv8[k], chx_s[(8 * q + k) * 97 + ls + 16 + u], a);
            a += __shfl_xor(a, 1);
            a += __shfl_xor(a, 2);
            if (u == 0) dot_self = a;
            else if (q == 0) dots_s[ls * 19 + u] = a;
        }
    }

    float uq_l = uqe[ls + 16];
    float dsv_l = dsve[ls + 16];
    float cmask = maskf[ls + 16];

    int tb = 16 * q;
    float st[16];
#pragma unroll
    for (int j = 0; j < 16; ++j) st[j] = 0.f;
#pragma unroll 2
    for (int d = 0; d < Dq; ++d) {
        float cv = cr_s[ls * 36 + d];
        const float4* r4 = (const float4*)&tts_s[d * 64 + tb];
        float4 r0 = r4[0], r1 = r4[1], r2 = r4[2], r3 = r4[3];
        st[0]  = fmaf(cv, r0.x, st[0]);  st[1]  = fmaf(cv, r0.y, st[1]);
        st[2]  = fmaf(cv, r0.z, st[2]);  st[3]  = fmaf(cv, r0.w, st[3]);
        st[4]  = fmaf(cv, r1.x, st[4]);  st[5]  = fmaf(cv, r1.y, st[5]);
        st[6]  = fmaf(cv, r1.z, st[6]);  st[7]  = fmaf(cv, r1.w, st[7]);
        st[8]  = fmaf(cv, r2.x, st[8]);  st[9]  = fmaf(cv, r2.y, st[9]);
        st[10] = fmaf(cv, r2.z, st[10]); st[11] = fmaf(cv, r2.w, st[11]);
        st[12] = fmaf(cv, r3.x, st[12]); st[13] = fmaf(cv, r3.y, st[13]);
        st[14] = fmaf(cv, r3.z, st[14]); st[15] = fmaf(cv, r3.w, st[15]);
    }
#pragma unroll
    for (int j = 0; j < 16; ++j)
        st[j] = leaky(uq_l + dts[tb + j] + st[j]);

    int nv = (q == 0) ? 5 : 4;
    float su[4];
#pragma unroll
    for (int j = 0; j < 4; ++j) {
        int u = q + 1 + 4 * j;
        bool ok = (pl + u < Lq) && (maskf[ls + 16 + u] > 0.5f);
        su[j] = ok ? leaky(uqe[ls + 16 + u] + dsv_l + dots_s[ls * 19 + u])
                   : MASK_FILL;
    }

    float m = st[0];
#pragma unroll
    for (int j = 1; j < 16; ++j) m = fmaxf(m, st[j]);
#pragma unroll
    for (int j = 0; j < 5; ++j) {
        if (j < nv) {
            int v = q + 4 * j;
            if ((pl + v >= 16) && (cmask > 0.5f))
                m = fmaxf(m, leaky(uq_l + dsve[ls + v] + dot_self));
        }
    }
#pragma unroll
    for (int j = 0; j < 4; ++j) m = fmaxf(m, su[j]);
    m = fmaxf(m, __shfl_xor(m, 1));
    m = fmaxf(m, __shfl_xor(m, 2));
    float sum = 0.f, wself = 0.f;
#pragma unroll
    for (int j = 0; j < 16; ++j) { st[j] = __expf(st[j] - m); sum += st[j]; }
#pragma unroll
    for (int j = 0; j < 5; ++j) {
        if (j < nv) {
            int v = q + 4 * j;
            if ((pl + v >= 16) && (cmask > 0.5f)) {
                float e = __expf(leaky(uq_l + dsve[ls + v] + dot_self) - m);
                wself += e; sum += e;
            }
        }
    }
#pragma unroll
    for (int j = 0; j < 4; ++j)  { su[j] = __expf(su[j] - m); sum += su[j]; }
    sum += __shfl_xor(sum, 1);
    sum += __shfl_xor(sum, 2);
    float inv = 1.f / sum;
#pragma unroll
    for (int j = 0; j < 16; ++j) st[j] *= inv;
    wself *= inv;
#pragma unroll
    for (int j = 0; j < 4; ++j)  su[j] *= inv;

    float* dstrow = update + (size_t)(b * Lq + pl) * Hq + n * Dq;
#pragma unroll
    for (int c = 0; c < 4; ++c) {
        float u8[8];
#pragma unroll
        for (int e = 0; e < 8; ++e) u8[e] = 0.f;
#pragma unroll 2
        for (int j = 0; j < 16; ++j) {
            const float* vp = &tts2_s[(tb + j) * 36 + 4 * q + 8 * c];
            float4 a0 = ((const float4*)vp)[0];
            float4 a1 = ((const float4*)vp)[1];
            float wt = st[j];
            u8[0] = fmaf(wt, a0.x, u8[0]); u8[1] = fmaf(wt, a0.y, u8[1]);
            u8[2] = fmaf(wt, a0.z, u8[2]); u8[3] = fmaf(wt, a0.w, u8[3]);
            u8[4] = fmaf(wt, a1.x, u8[4]); u8[5] = fmaf(wt, a1.y, u8[5]);
            u8[6] = fmaf(wt, a1.z, u8[6]); u8[7] = fmaf(wt, a1.w, u8[7]);
        }
#pragma unroll
        for (int e = 0; e < 8; ++e)
            u8[e] = fmaf(wself, chx_s[(8 * c + e) * 97 + ls + 16], u8[e]);
#pragma unroll
        for (int j = 0; j < 4; ++j) {
            float wu = su[j];
            int u = q + 1 + 4 * j;
#pragma unroll
            for (int e = 0; e < 8; ++e)
                u8[e] = fmaf(wu, chx_s[(8 * c + e) * 97 + ls + 16 + u], u8[e]);
        }
#pragma unroll
        for (int e = 0; e < 8; ++e) {
            u8[e] += __shfl_xor(u8[e], 1);
            u8[e] += __shfl_xor(u8[e], 2);
        }
        if (q == c) {
            ((float4*)(dstrow + 8 * c))[0] = make_float4(u8[0], u8[1], u8[2], u8[3]);
            ((float4*)(dstrow + 8 * c))[1] = make_float4(u8[4], u8[5], u8[6], u8[7]);
        }
    }
}

// ---------------- output GEMM via MFMA + tanh ----------------
__global__ void __launch_bounds__(256) k_out(
        const float* __restrict__ update, const float* __restrict__ ctx,
        const uint16_t* __restrict__ wp_hi, const uint16_t* __restrict__ wp_lo,
        const float* __restrict__ bo, float* __restrict__ out) {
    int row0 = blockIdx.x * MB;
    int tid = threadIdx.x;
    int w = tid >> 6, l = tid & 63;
    __shared__ __align__(16) char smem_raw[33792];
    uint16_t* a_hi = (uint16_t*)smem_raw;
    uint16_t* a_lo = a_hi + MB * APAD;

    {
        const float4* s0 = (const float4*)(update + (size_t)row0 * Hq);
        const float4* s1 = (const float4*)(ctx + (size_t)row0 * Hq);
#pragma unroll
        for (int j = 0; j < 8; ++j) {
            int f = tid + j * 256;
            int r = f >> 6, cg = f & 63;
            float4 a = s0[f], bv = s1[f];
            float4 v; v.x = a.x + bv.x; v.y = a.y + bv.y;
            v.z = a.z + bv.z; v.w = a.w + bv.w;
            uint16_t h0 = f2bf(v.x), h1 = f2bf(v.y), h2 = f2bf(v.z), h3 = f2bf(v.w);
            ushort4 hh = {h0, h1, h2, h3};
            ushort4 ll = {f2bf(v.x - bf2f(h0)), f2bf(v.y - bf2f(h1)),
                          f2bf(v.z - bf2f(h2)), f2bf(v.w - bf2f(h3))};
            *(ushort4*)&a_hi[r * APAD + cg * 4] = hh;
            *(ushort4*)&a_lo[r * APAD + cg * 4] = ll;
        }
    }
    __syncthreads();

    int wr = (w >> 1) * 16;
    int nt0 = (w & 1) * 8;
    int m = l & 15, quad = l >> 4;
    f32x4 acc[8];
#pragma unroll
    for (int t = 0; t < 8; ++t) acc[t] = (f32x4){0.f, 0.f, 0.f, 0.f};
    for (int kc = 0; kc < 8; ++kc) {
        short8 ah = *(const short8*)&a_hi[(wr + m) * APAD + kc * 32 + quad * 8];
        short8 al = *(const short8*)&a_lo[(wr + m) * APAD + kc * 32 + quad * 8];
#pragma unroll
        for (int t = 0; t < 8; ++t) {
            int fragi = (nt0 + t) * 8 + kc;
            short8 wh = *(const short8*)&wp_hi[fragi * 512 + l * 8];
            short8 wl = *(const short8*)&wp_lo[fragi * 512 + l * 8];
            acc[t] = __builtin_amdgcn_mfma_f32_16x16x32_bf16(ah, wh, acc[t], 0, 0, 0);
            acc[t] = __builtin_amdgcn_mfma_f32_16x16x32_bf16(ah, wl, acc[t], 0, 0, 0);
            acc[t] = __builtin_amdgcn_mfma_f32_16x16x32_bf16(al, wh, acc[t], 0, 0, 0);
        }
    }
    // epilogue: tanh + direct store (C layout: row=quad*4+r, col=16*(nt0+t)+m)
#pragma unroll
    for (int t = 0; t < 8; ++t) {
        int col = (nt0 + t) * 16 + m;
        float bv = bo[col];
#pragma unroll
        for (int r = 0; r < 4; ++r)
            out[(size_t)(row0 + wr + quad * 4 + r) * Hq + col] = tanhf(acc[t][r] + bv);
    }
}

extern "C" void kernel_launch(void* const* d_in, const int* in_sizes, int n_in,
                              void* d_out, int out_size, void* d_ws, size_t ws_size,
                              hipStream_t stream) {
    const float* context   = (const float*)d_in[0];
    const float* types     = (const float*)d_in[1];
    const unsigned char* cmask = (const unsigned char*)d_in[2];
    const float* W_types   = (const float*)d_in[3];
    const float* b_types   = (const float*)d_in[4];
    const float* W_context = (const float*)d_in[5];
    const float* b_context = (const float*)d_in[6];
    const float* upon      = (const float*)d_in[7];
    const float* down      = (const float*)d_in[8];
    const float* cross     = (const float*)d_in[9];
    const float* W_out     = (const float*)d_in[10];
    const float* b_out     = (const float*)d_in[11];
    float* out = (float*)d_out;
    float* ws  = (float*)d_ws;

    // ws: ctx_hT (16MB) + update (16MB) + W packs (512 KB) = 33.05 MB
    // (proven-safe envelope is >= 34.87 MB from R1/R2)
    float* ctx_hT   = ws;             // [b][n][d][l]
    float* update   = ws + 4194304;
    uint16_t* wcp_hi = (uint16_t*)(ws + 8388608);
    uint16_t* wcp_lo = wcp_hi + 65536;
    uint16_t* wop_hi = wcp_hi + 131072;
    uint16_t* wop_lo = wcp_hi + 196608;

    // Small intermediates in d_out scratch (k_out overwrites all of d_out last).
    float* types_h  = out;            // 65536   [b][t][h]
    float* types_hT = out + 65536;    // 65536   [b][n][d][t]
    float* down_t   = out + 131072;   // 2048
    float* uqp      = out + 133120;   // 131072
    float* dsvp     = out + 264192;   // 131072

    k_wprep<<<128, 256, 0, stream>>>(W_context, W_out, wcp_hi, wcp_lo, wop_hi, wop_lo);
    k_types<<<Bq * Tq, Hq, 0, stream>>>(types, W_types, b_types, down,
                                        types_h, types_hT, down_t);
    k_ctx<<<Bq * Lq / MB, 256, 0, stream>>>(context, wcp_hi, wcp_lo, b_context,
                                            upon, down, ctx_hT, uqp, dsvp);
    k_attn<<<Bq * NHq * (Lq / TLq), 256, 0, stream>>>(ctx_hT, types_h, types_hT, cross,
                                                      uqp, dsvp, down_t, cmask, update);
    k_out<<<Bq * Lq / MB, 256, 0, stream>>>(update, context, wop_hi, wop_lo, b_out, out);
}

// Round 12
// 186.459 us; speedup vs baseline: 1.2160x; 1.1018x over previous
//
#include <hip/hip_runtime.h>
#include <cstdint>

#define Bq 4
#define Lq 4096
#define Hq 256
#define NHq 8
#define Tq 64
#define WINq 16
#define Dq 32
#define NSLOTS 33
#define NEG_SLOPE 5.0f
#define MASK_FILL -1e12f
#define TLq 64         // l-tile for k_attn
#define MB 16          // rows per block for MFMA GEMMs (1024 blocks -> 4/CU)

typedef __attribute__((ext_vector_type(8))) short short8;
typedef __attribute__((ext_vector_type(4))) float f32x4;

__device__ __forceinline__ float leaky(float x) { return x >= 0.f ? x : NEG_SLOPE * x; }

__device__ __forceinline__ uint16_t f2bf(float x) {   // RNE f32->bf16 bits
    uint32_t u = __float_as_uint(x);
    uint32_t r = (u + 0x7fffu + ((u >> 16) & 1u)) >> 16;
    return (uint16_t)r;
}
__device__ __forceinline__ float bf2f(uint16_t h) {
    return __uint_as_float(((uint32_t)h) << 16);
}

// ---------------- W packing: MFMA B-fragment order, hi/lo bf16 ----------------
// dst[fragi*512 + l*8 + j] = W[kc*32 + (l>>4)*8 + j][nt*16 + (l&15)], fragi = nt*8+kc
__global__ void k_wprep(const float* __restrict__ Wc, const float* __restrict__ Wo,
                        uint16_t* __restrict__ pc_hi, uint16_t* __restrict__ pc_lo,
                        uint16_t* __restrict__ po_hi, uint16_t* __restrict__ po_lo) {
    int wsel = blockIdx.x >> 6;
    int blk = blockIdx.x & 63;
    const float* W = wsel ? Wo : Wc;
    uint16_t* ph = wsel ? po_hi : pc_hi;
    uint16_t* pl = wsel ? po_lo : pc_lo;
    int base = blk * 1024;
    for (int idx = base + threadIdx.x; idx < base + 1024; idx += 256) {
        int j = idx & 7, l = (idx >> 3) & 63, fragi = idx >> 9;
        int kc = fragi & 7, nt = fragi >> 3;
        int k = kc * 32 + (l >> 4) * 8 + j;
        int c = nt * 16 + (l & 15);
        float x = W[k * Hq + c];
        uint16_t h = f2bf(x);
        ph[idx] = h;
        pl[idx] = f2bf(x - bf2f(h));
    }
}

// ---------------- types projection + down_t + transposed copy ----------------
__global__ void k_types(const float* __restrict__ types, const float* __restrict__ Wt,
                        const float* __restrict__ bt, const float* __restrict__ down,
                        float* __restrict__ types_h, float* __restrict__ types_hT,
                        float* __restrict__ down_t) {
    int row = blockIdx.x;          // b*T + t
    int h = threadIdx.x;
    int b = row >> 6, t = row & 63;
    __shared__ float in[Hq];
    __shared__ float outr[Hq];
    in[h] = types[(size_t)row * Hq + h];
    __syncthreads();
    float acc = bt[h];
    for (int k = 0; k < Hq; k += 4) {
        float4 iv = *(const float4*)&in[k];
        acc = fmaf(iv.x, Wt[(k + 0) * Hq + h], acc);
        acc = fmaf(iv.y, Wt[(k + 1) * Hq + h], acc);
        acc = fmaf(iv.z, Wt[(k + 2) * Hq + h], acc);
        acc = fmaf(iv.w, Wt[(k + 3) * Hq + h], acc);
    }
    types_h[(size_t)row * Hq + h] = acc;
    types_hT[(size_t)(b * Hq + h) * Tq + t] = acc;   // [b][n][d][t]
    outr[h] = acc;
    __syncthreads();
    if (h < NHq) {
        float s = 0.f;
        for (int d = 0; d < Dq; ++d) s += outr[h * Dq + d] * down[h * Dq + d];
        down_t[(b * NHq + h) * Tq + t] = s;
    }
}

// ---------------- context projection via MFMA (bf16 hi/lo split) ----------------
// MB=16 rows/block, 4 waves; wave w owns col-tiles nt0=4w..4w+3 (A-tile shared)
#define APAD 264       // bf16 row stride for A tiles
#define OPAD 258       // f32 row stride for output staging
__global__ void __launch_bounds__(256) k_ctx(
        const float* __restrict__ ctx,
        const uint16_t* __restrict__ wp_hi, const uint16_t* __restrict__ wp_lo,
        const float* __restrict__ bc, const float* __restrict__ upon,
        const float* __restrict__ down,
        float* __restrict__ ctx_hT, float* __restrict__ uq,
        float* __restrict__ dsv) {
    int row0 = blockIdx.x * MB;
    int b = row0 >> 12, l0 = row0 & (Lq - 1);
    int tid = threadIdx.x;
    int w = tid >> 6, l = tid & 63;
    __shared__ __align__(16) char smem_raw[MB * APAD * 4];   // 16.9 KB
    uint16_t* a_hi = (uint16_t*)smem_raw;            // [16][APAD]
    uint16_t* a_lo = a_hi + MB * APAD;
    float* outb = (float*)smem_raw;                  // reused: [16][OPAD]

    // stage + split rows (16*64 = 1024 float4, 4/thread)
    {
        const float4* src = (const float4*)(ctx + (size_t)row0 * Hq);
#pragma unroll
        for (int j = 0; j < 4; ++j) {
            int f = tid + j * 256;
            int r = f >> 6, cg = f & 63;
            float4 v = src[f];
            uint16_t h0 = f2bf(v.x), h1 = f2bf(v.y), h2 = f2bf(v.z), h3 = f2bf(v.w);
            ushort4 hh = {h0, h1, h2, h3};
            ushort4 ll = {f2bf(v.x - bf2f(h0)), f2bf(v.y - bf2f(h1)),
                          f2bf(v.z - bf2f(h2)), f2bf(v.w - bf2f(h3))};
            *(ushort4*)&a_hi[r * APAD + cg * 4] = hh;
            *(ushort4*)&a_lo[r * APAD + cg * 4] = ll;
        }
    }
    __syncthreads();

    int nt0 = w * 4;               // wave col-tile base
    int m = l & 15, quad = l >> 4;
    f32x4 acc[4];
#pragma unroll
    for (int t = 0; t < 4; ++t) acc[t] = (f32x4){0.f, 0.f, 0.f, 0.f};
    for (int kc = 0; kc < 8; ++kc) {
        short8 ah = *(const short8*)&a_hi[m * APAD + kc * 32 + quad * 8];
        short8 al = *(const short8*)&a_lo[m * APAD + kc * 32 + quad * 8];
#pragma unroll
        for (int t = 0; t < 4; ++t) {
            int fragi = (nt0 + t) * 8 + kc;
            short8 wh = *(const short8*)&wp_hi[fragi * 512 + l * 8];
            short8 wl = *(const short8*)&wp_lo[fragi * 512 + l * 8];
            acc[t] = __builtin_amdgcn_mfma_f32_16x16x32_bf16(ah, wh, acc[t], 0, 0, 0);
            acc[t] = __builtin_amdgcn_mfma_f32_16x16x32_bf16(ah, wl, acc[t], 0, 0, 0);
            acc[t] = __builtin_amdgcn_mfma_f32_16x16x32_bf16(al, wh, acc[t], 0, 0, 0);
        }
    }
    __syncthreads();   // all a_hi/a_lo reads done; reuse smem as outb

    // write C (+bias) to LDS staging (row=quad*4+r, col=(nt0+t)*16+m)
#pragma unroll
    for (int t = 0; t < 4; ++t) {
        int col = (nt0 + t) * 16 + m;
        float bv = bc[col];
#pragma unroll
        for (int r = 0; r < 4; ++r)
            outb[(quad * 4 + r) * OPAD + col] = acc[t][r] + bv;
    }
    __syncthreads();

    // uq / dsv: threads 0..127 -> (r, n)
    if (tid < MB * NHq) {
        int r = tid >> 3, n = tid & 7;
        float su = 0.f, sd = 0.f;
        for (int d = 0; d < Dq; ++d) {
            float v = outb[r * OPAD + n * Dq + d];
            su += v * upon[n * Dq + d];
            sd += v * down[n * Dq + d];
        }
        uq[(b * NHq + n) * Lq + l0 + r] = su;
        dsv[(b * NHq + n) * Lq + l0 + r] = sd;
    }
    // transposed store: thread tid owns channel tid, writes 16 l's
    {
        float* dst = ctx_hT + (size_t)(b * Hq + tid) * Lq + l0;
#pragma unroll
        for (int j = 0; j < MB / 4; ++j) {
            float4 o;
            o.x = outb[(4 * j + 0) * OPAD + tid];
            o.y = outb[(4 * j + 1) * OPAD + tid];
            o.z = outb[(4 * j + 2) * OPAD + tid];
            o.w = outb[(4 * j + 3) * OPAD + tid];
            ((float4*)dst)[j] = o;
        }
    }
}

// ---------------- attention: tiled (b, n, 64 l's) per block (unchanged R9) ----
__global__ void __launch_bounds__(256) k_attn(
        const float* __restrict__ ctx_hT, const float* __restrict__ types_h,
        const float* __restrict__ types_hT, const float* __restrict__ cross,
        const float* __restrict__ uq, const float* __restrict__ dsv,
        const float* __restrict__ dt, const unsigned char* __restrict__ maskp,
        float* __restrict__ update) {
    int blk = blockIdx.x;
    int lt = blk & 63, n = (blk >> 6) & 7, b = blk >> 9;
    int l0 = lt * TLq;
    int tid = threadIdx.x;
    int ls = tid >> 2;
    int q  = tid & 3;
    int pl = l0 + ls;
    bool mask_b8 = (maskp[1] != 0);

    __shared__ float chx_s[32 * 97];
    __shared__ float crs_s[32 * 36];
    __shared__ float cr_s[64 * 36];
    __shared__ float dots_s[64 * 19];
    __shared__ float tts_s[32 * 64];
    __shared__ float tts2_s[64 * 36 + 16];
    __shared__ float uqe[96], dsve[96], maskf[96], dts[64];

    {
        int d = tid >> 3, k = tid & 7;
        const float* grow = ctx_hT + ((size_t)(b * NHq + n) * Dq + d) * Lq;
        float* lrow = &chx_s[d * 97 + k * 12];
        if (l0 >= 16 && l0 <= Lq - 80) {
            const float4* g = (const float4*)(grow + (l0 - 16) + k * 12);
            float4 v0 = g[0], v1 = g[1], v2 = g[2];
            lrow[0] = v0.x; lrow[1] = v0.y; lrow[2]  = v0.z; lrow[3]  = v0.w;
            lrow[4] = v1.x; lrow[5] = v1.y; lrow[6]  = v1.z; lrow[7]  = v1.w;
            lrow[8] = v2.x; lrow[9] = v2.y; lrow[10] = v2.z; lrow[11] = v2.w;
        } else {
#pragma unroll
            for (int m = 0; m < 12; ++m) {
                int gl = l0 - 16 + k * 12 + m;
                int glw = (gl < 0) ? gl + Lq : ((gl >= Lq) ? gl - Lq : gl);
                lrow[m] = grow[glw];
            }
        }
    }
    {
        float4 v = ((const float4*)(cross + n * (Dq * Dq)))[tid];
        float* p = &crs_s[(tid >> 3) * 36 + (tid & 7) * 4];
        p[0] = v.x; p[1] = v.y; p[2] = v.z; p[3] = v.w;
    }
    {
        const float4* src = (const float4*)(types_hT + (size_t)(b * NHq + n) * Dq * Tq);
        float4* dst = (float4*)tts_s;
        dst[tid] = src[tid];
        dst[tid + 256] = src[tid + 256];
    }
    {
        int t = tid >> 2, c4 = tid & 3;
        const float4* src = (const float4*)(types_h + (size_t)(b * Tq + t) * Hq
                                            + n * Dq + 8 * c4);
        float* p = &tts2_s[t * 36 + 4 * (t >> 4) + 8 * c4];
        ((float4*)p)[0] = src[0];
        ((float4*)p)[1] = src[1];
    }
    if (tid < 96) {
        int gl = l0 - 16 + tid;
        int glw = (gl < 0) ? gl + Lq : ((gl >= Lq) ? gl - Lq : gl);
        uqe[tid] = uq[(b * NHq + n) * Lq + glw];
        unsigned char mb = mask_b8 ? maskp[b * Lq + glw]
                                   : maskp[(size_t)(b * Lq + glw) * 4];
        maskf[tid] = mb ? 1.f : 0.f;
    } else if (tid < 192) {
        int j = tid - 96;
        int gl = l0 - 16 + j;
        int glw = (gl < 0) ? gl + Lq : ((gl >= Lq) ? gl - Lq : gl);
        dsve[j] = dsv[(b * NHq + n) * Lq + glw];
    } else {
        dts[tid - 192] = dt[(b * NHq + n) * Tq + (tid - 192)];
    }
    __syncthreads();

    {
        float a[8];
#pragma unroll
        for (int ii = 0; ii < 8; ++ii) a[ii] = 0.f;
#pragma unroll 2
        for (int d = 0; d < Dq; ++d) {
            float chv = chx_s[d * 97 + ls + 16];
            const float4* cp = (const float4*)(&crs_s[d * 36 + 8 * q]);
            float4 c0 = cp[0], c1 = cp[1];
            a[0] = fmaf(chv, c0.x, a[0]); a[1] = fmaf(chv, c0.y, a[1]);
            a[2] = fmaf(chv, c0.z, a[2]); a[3] = fmaf(chv, c0.w, a[3]);
            a[4] = fmaf(chv, c1.x, a[4]); a[5] = fmaf(chv, c1.y, a[5]);
            a[6] = fmaf(chv, c1.z, a[6]); a[7] = fmaf(chv, c1.w, a[7]);
        }
        float4* wp = (float4*)(&cr_s[ls * 36 + 8 * q]);
        wp[0] = make_float4(a[0], a[1], a[2], a[3]);
        wp[1] = make_float4(a[4], a[5], a[6], a[7]);
    }

    float dot_self;
    {
        float cv8[8];
#pragma unroll
        for (int k = 0; k < 8; ++k) cv8[k] = cr_s[ls * 36 + 8 * q + k];
#pragma unroll
        for (int u = 0; u < 17; ++u) {
            float a = 0.f;
#pragma unroll
            for (int k = 0; k < 8; ++k)
                a = fmaf(cv8[k], chx_s[(8 * q + k) * 97 + ls + 16 + u], a);
            a += __shfl_xor(a, 1);
            a += __shfl_xor(a, 2);
            if (u == 0) dot_self = a;
            else if (q == 0) dots_s[ls * 19 + u] = a;
        }
    }

    float uq_l = uqe[ls + 16];
    float dsv_l = dsve[ls + 16];
    float cmask = maskf[ls + 16];

    int tb = 16 * q;
    float st[16];
#pragma unroll
    for (int j = 0; j < 16; ++j) st[j] = 0.f;
#pragma unroll 2
    for (int d = 0; d < Dq; ++d) {
        float cv = cr_s[ls * 36 + d];
        const float4* r4 = (const float4*)&tts_s[d * 64 + tb];
        float4 r0 = r4[0], r1 = r4[1], r2 = r4[2], r3 = r4[3];
        st[0]  = fmaf(cv, r0.x, st[0]);  st[1]  = fmaf(cv, r0.y, st[1]);
        st[2]  = fmaf(cv, r0.z, st[2]);  st[3]  = fmaf(cv, r0.w, st[3]);
        st[4]  = fmaf(cv, r1.x, st[4]);  st[5]  = fmaf(cv, r1.y, st[5]);
        st[6]  = fmaf(cv, r1.z, st[6]);  st[7]  = fmaf(cv, r1.w, st[7]);
        st[8]  = fmaf(cv, r2.x, st[8]);  st[9]  = fmaf(cv, r2.y, st[9]);
        st[10] = fmaf(cv, r2.z, st[10]); st[11] = fmaf(cv, r2.w, st[11]);
        st[12] = fmaf(cv, r3.x, st[12]); st[13] = fmaf(cv, r3.y, st[13]);
        st[14] = fmaf(cv, r3.z, st[14]); st[15] = fmaf(cv, r3.w, st[15]);
    }
#pragma unroll
    for (int j = 0; j < 16; ++j)
        st[j] = leaky(uq_l + dts[tb + j] + st[j]);

    int nv = (q == 0) ? 5 : 4;
    float su[4];
#pragma unroll
    for (int j = 0; j < 4; ++j) {
        int u = q + 1 + 4 * j;
        bool ok = (pl + u < Lq) && (maskf[ls + 16 + u] > 0.5f);
        su[j] = ok ? leaky(uqe[ls + 16 + u] + dsv_l + dots_s[ls * 19 + u])
                   : MASK_FILL;
    }

    float m = st[0];
#pragma unroll
    for (int j = 1; j < 16; ++j) m = fmaxf(m, st[j]);
#pragma unroll
    for (int j = 0; j < 5; ++j) {
        if (j < nv) {
            int v = q + 4 * j;
            if ((pl + v >= 16) && (cmask > 0.5f))
                m = fmaxf(m, leaky(uq_l + dsve[ls + v] + dot_self));
        }
    }
#pragma unroll
    for (int j = 0; j < 4; ++j) m = fmaxf(m, su[j]);
    m = fmaxf(m, __shfl_xor(m, 1));
    m = fmaxf(m, __shfl_xor(m, 2));
    float sum = 0.f, wself = 0.f;
#pragma unroll
    for (int j = 0; j < 16; ++j) { st[j] = __expf(st[j] - m); sum += st[j]; }
#pragma unroll
    for (int j = 0; j < 5; ++j) {
        if (j < nv) {
            int v = q + 4 * j;
            if ((pl + v >= 16) && (cmask > 0.5f)) {
                float e = __expf(leaky(uq_l + dsve[ls + v] + dot_self) - m);
                wself += e; sum += e;
            }
        }
    }
#pragma unroll
    for (int j = 0; j < 4; ++j)  { su[j] = __expf(su[j] - m); sum += su[j]; }
    sum += __shfl_xor(sum, 1);
    sum += __shfl_xor(sum, 2);
    float inv = 1.f / sum;
#pragma unroll
    for (int j = 0; j < 16; ++j) st[j] *= inv;
    wself *= inv;
#pragma unroll
    for (int j = 0; j < 4; ++j)  su[j] *= inv;

    float* dstrow = update + (size_t)(b * Lq + pl) * Hq + n * Dq;
#pragma unroll
    for (int c = 0; c < 4; ++c) {
        float u8[8];
#pragma unroll
        for (int e = 0; e < 8; ++e) u8[e] = 0.f;
#pragma unroll 2
        for (int j = 0; j < 16; ++j) {
            const float* vp = &tts2_s[(tb + j) * 36 + 4 * q + 8 * c];
            float4 a0 = ((const float4*)vp)[0];
            float4 a1 = ((const float4*)vp)[1];
            float wt = st[j];
            u8[0] = fmaf(wt, a0.x, u8[0]); u8[1] = fmaf(wt, a0.y, u8[1]);
            u8[2] = fmaf(wt, a0.z, u8[2]); u8[3] = fmaf(wt, a0.w, u8[3]);
            u8[4] = fmaf(wt, a1.x, u8[4]); u8[5] = fmaf(wt, a1.y, u8[5]);
            u8[6] = fmaf(wt, a1.z, u8[6]); u8[7] = fmaf(wt, a1.w, u8[7]);
        }
#pragma unroll
        for (int e = 0; e < 8; ++e)
            u8[e] = fmaf(wself, chx_s[(8 * c + e) * 97 + ls + 16], u8[e]);
#pragma unroll
        for (int j = 0; j < 4; ++j) {
            float wu = su[j];
            int u = q + 1 + 4 * j;
#pragma unroll
            for (int e = 0; e < 8; ++e)
                u8[e] = fmaf(wu, chx_s[(8 * c + e) * 97 + ls + 16 + u], u8[e]);
        }
#pragma unroll
        for (int e = 0; e < 8; ++e) {
            u8[e] += __shfl_xor(u8[e], 1);
            u8[e] += __shfl_xor(u8[e], 2);
        }
        if (q == c) {
            ((float4*)(dstrow + 8 * c))[0] = make_float4(u8[0], u8[1], u8[2], u8[3]);
            ((float4*)(dstrow + 8 * c))[1] = make_float4(u8[4], u8[5], u8[6], u8[7]);
        }
    }
}

// ---------------- output GEMM via MFMA + tanh ----------------
__global__ void __launch_bounds__(256) k_out(
        const float* __restrict__ update, const float* __restrict__ ctx,
        const uint16_t* __restrict__ wp_hi, const uint16_t* __restrict__ wp_lo,
        const float* __restrict__ bo, float* __restrict__ out) {
    int row0 = blockIdx.x * MB;
    int tid = threadIdx.x;
    int w = tid >> 6, l = tid & 63;
    __shared__ __align__(16) char smem_raw[MB * APAD * 4];
    uint16_t* a_hi = (uint16_t*)smem_raw;
    uint16_t* a_lo = a_hi + MB * APAD;

    {
        const float4* s0 = (const float4*)(update + (size_t)row0 * Hq);
        const float4* s1 = (const float4*)(ctx + (size_t)row0 * Hq);
#pragma unroll
        for (int j = 0; j < 4; ++j) {
            int f = tid + j * 256;
            int r = f >> 6, cg = f & 63;
            float4 a = s0[f], bv = s1[f];
            float4 v; v.x = a.x + bv.x; v.y = a.y + bv.y;
            v.z = a.z + bv.z; v.w = a.w + bv.w;
            uint16_t h0 = f2bf(v.x), h1 = f2bf(v.y), h2 = f2bf(v.z), h3 = f2bf(v.w);
            ushort4 hh = {h0, h1, h2, h3};
            ushort4 ll = {f2bf(v.x - bf2f(h0)), f2bf(v.y - bf2f(h1)),
                          f2bf(v.z - bf2f(h2)), f2bf(v.w - bf2f(h3))};
            *(ushort4*)&a_hi[r * APAD + cg * 4] = hh;
            *(ushort4*)&a_lo[r * APAD + cg * 4] = ll;
        }
    }
    __syncthreads();

    int nt0 = w * 4;
    int m = l & 15, quad = l >> 4;
    f32x4 acc[4];
#pragma unroll
    for (int t = 0; t < 4; ++t) acc[t] = (f32x4){0.f, 0.f, 0.f, 0.f};
    for (int kc = 0; kc < 8; ++kc) {
        short8 ah = *(const short8*)&a_hi[m * APAD + kc * 32 + quad * 8];
        short8 al = *(const short8*)&a_lo[m * APAD + kc * 32 + quad * 8];
#pragma unroll
        for (int t = 0; t < 4; ++t) {
            int fragi = (nt0 + t) * 8 + kc;
            short8 wh = *(const short8*)&wp_hi[fragi * 512 + l * 8];
            short8 wl = *(const short8*)&wp_lo[fragi * 512 + l * 8];
            acc[t] = __builtin_amdgcn_mfma_f32_16x16x32_bf16(ah, wh, acc[t], 0, 0, 0);
            acc[t] = __builtin_amdgcn_mfma_f32_16x16x32_bf16(ah, wl, acc[t], 0, 0, 0);
            acc[t] = __builtin_amdgcn_mfma_f32_16x16x32_bf16(al, wh, acc[t], 0, 0, 0);
        }
    }
    // epilogue: tanh + direct store (C layout: row=quad*4+r, col=16*(nt0+t)+m)
#pragma unroll
    for (int t = 0; t < 4; ++t) {
        int col = (nt0 + t) * 16 + m;
        float bv = bo[col];
#pragma unroll
        for (int r = 0; r < 4; ++r)
            out[(size_t)(row0 + quad * 4 + r) * Hq + col] = tanhf(acc[t][r] + bv);
    }
}

extern "C" void kernel_launch(void* const* d_in, const int* in_sizes, int n_in,
                              void* d_out, int out_size, void* d_ws, size_t ws_size,
                              hipStream_t stream) {
    const float* context   = (const float*)d_in[0];
    const float* types     = (const float*)d_in[1];
    const unsigned char* cmask = (const unsigned char*)d_in[2];
    const float* W_types   = (const float*)d_in[3];
    const float* b_types   = (const float*)d_in[4];
    const float* W_context = (const float*)d_in[5];
    const float* b_context = (const float*)d_in[6];
    const float* upon      = (const float*)d_in[7];
    const float* down      = (const float*)d_in[8];
    const float* cross     = (const float*)d_in[9];
    const float* W_out     = (const float*)d_in[10];
    const float* b_out     = (const float*)d_in[11];
    float* out = (float*)d_out;
    float* ws  = (float*)d_ws;

    // ws: ctx_hT (16MB) + update (16MB) + W packs (512 KB) = 33.05 MB
    float* ctx_hT   = ws;             // [b][n][d][l]
    float* update   = ws + 4194304;
    uint16_t* wcp_hi = (uint16_t*)(ws + 8388608);
    uint16_t* wcp_lo = wcp_hi + 65536;
    uint16_t* wop_hi = wcp_hi + 131072;
    uint16_t* wop_lo = wcp_hi + 196608;

    // Small intermediates in d_out scratch (k_out overwrites all of d_out last).
    float* types_h  = out;            // 65536   [b][t][h]
    float* types_hT = out + 65536;    // 65536   [b][n][d][t]
    float* down_t   = out + 131072;   // 2048
    float* uqp      = out + 133120;   // 131072
    float* dsvp     = out + 264192;   // 131072

    k_wprep<<<128, 256, 0, stream>>>(W_context, W_out, wcp_hi, wcp_lo, wop_hi, wop_lo);
    k_types<<<Bq * Tq, Hq, 0, stream>>>(types, W_types, b_types, down,
                                        types_h, types_hT, down_t);
    k_ctx<<<Bq * Lq / MB, 256, 0, stream>>>(context, wcp_hi, wcp_lo, b_context,
                                            upon, down, ctx_hT, uqp, dsvp);
    k_attn<<<Bq * NHq * (Lq / TLq), 256, 0, stream>>>(ctx_hT, types_h, types_hT, cross,
                                                      uqp, dsvp, down_t, cmask, update);
    k_out<<<Bq * Lq / MB, 256, 0, stream>>>(update, context, wop_hi, wop_lo, b_out, out);
}

// Round 13
// 183.297 us; speedup vs baseline: 1.2370x; 1.0172x over previous
//
#include <hip/hip_runtime.h>
#include <cstdint>

#define Bq 4
#define Lq 4096
#define Hq 256
#define NHq 8
#define Tq 64
#define WINq 16
#define Dq 32
#define NSLOTS 33
#define NEG_SLOPE 5.0f
#define MASK_FILL -1e12f
#define TLq 64         // l-tile for k_attn
#define MB 16          // rows per block for MFMA GEMMs (1024 blocks -> 4/CU)

typedef __attribute__((ext_vector_type(8))) short short8;
typedef __attribute__((ext_vector_type(4))) float f32x4;

__device__ __forceinline__ float leaky(float x) { return x >= 0.f ? x : NEG_SLOPE * x; }

__device__ __forceinline__ uint16_t f2bf(float x) {   // RNE f32->bf16 bits
    uint32_t u = __float_as_uint(x);
    uint32_t r = (u + 0x7fffu + ((u >> 16) & 1u)) >> 16;
    return (uint16_t)r;
}
__device__ __forceinline__ float bf2f(uint16_t h) {
    return __uint_as_float(((uint32_t)h) << 16);
}

// ------- merged prep: blocks 0..127 pack Wc/Wo; blocks 128..383 do types -------
// W pack: dst[fragi*512 + l*8 + j] = W[kc*32+(l>>4)*8+j][nt*16+(l&15)], fragi=nt*8+kc
__global__ void k_prep(const float* __restrict__ Wc, const float* __restrict__ Wo,
                       uint16_t* __restrict__ pc_hi, uint16_t* __restrict__ pc_lo,
                       uint16_t* __restrict__ po_hi, uint16_t* __restrict__ po_lo,
                       const float* __restrict__ types, const float* __restrict__ Wt,
                       const float* __restrict__ bt, const float* __restrict__ down,
                       float* __restrict__ types_h, float* __restrict__ types_hT,
                       float* __restrict__ down_t) {
    __shared__ float sin[Hq];
    __shared__ float outr[Hq];
    if (blockIdx.x < 128) {
        int wsel = blockIdx.x >> 6;
        int blk = blockIdx.x & 63;
        const float* W = wsel ? Wo : Wc;
        uint16_t* ph = wsel ? po_hi : pc_hi;
        uint16_t* pl = wsel ? po_lo : pc_lo;
        int base = blk * 1024;
        for (int idx = base + threadIdx.x; idx < base + 1024; idx += 256) {
            int j = idx & 7, l = (idx >> 3) & 63, fragi = idx >> 9;
            int kc = fragi & 7, nt = fragi >> 3;
            int k = kc * 32 + (l >> 4) * 8 + j;
            int c = nt * 16 + (l & 15);
            float x = W[k * Hq + c];
            uint16_t h = f2bf(x);
            ph[idx] = h;
            pl[idx] = f2bf(x - bf2f(h));
        }
        return;
    }
    // ---- types projection + down_t + transposed copy ----
    int row = blockIdx.x - 128;    // b*T + t
    int h = threadIdx.x;
    int b = row >> 6, t = row & 63;
    sin[h] = types[(size_t)row * Hq + h];
    __syncthreads();
    float acc = bt[h];
    for (int k = 0; k < Hq; k += 4) {
        float4 iv = *(const float4*)&sin[k];
        acc = fmaf(iv.x, Wt[(k + 0) * Hq + h], acc);
        acc = fmaf(iv.y, Wt[(k + 1) * Hq + h], acc);
        acc = fmaf(iv.z, Wt[(k + 2) * Hq + h], acc);
        acc = fmaf(iv.w, Wt[(k + 3) * Hq + h], acc);
    }
    types_h[(size_t)row * Hq + h] = acc;
    types_hT[(size_t)(b * Hq + h) * Tq + t] = acc;   // [b][n][d][t]
    outr[h] = acc;
    __syncthreads();
    if (h < NHq) {
        float s = 0.f;
        for (int d = 0; d < Dq; ++d) s += outr[h * Dq + d] * down[h * Dq + d];
        down_t[(b * NHq + h) * Tq + t] = s;
    }
}

// ---------------- context projection via MFMA (bf16 hi/lo split) ----------------
// MB=16 rows/block, 4 waves; wave w owns col-tiles nt0=4w..4w+3 (A-tile shared)
#define APAD 264       // bf16 row stride for A tiles
#define OPAD 258       // f32 row stride for output staging
__global__ void __launch_bounds__(256) k_ctx(
        const float* __restrict__ ctx,
        const uint16_t* __restrict__ wp_hi, const uint16_t* __restrict__ wp_lo,
        const float* __restrict__ bc, const float* __restrict__ upon,
        const float* __restrict__ down,
        float* __restrict__ ctx_hT, float* __restrict__ uq,
        float* __restrict__ dsv) {
    int row0 = blockIdx.x * MB;
    int b = row0 >> 12, l0 = row0 & (Lq - 1);
    int tid = threadIdx.x;
    int w = tid >> 6, l = tid & 63;
    __shared__ __align__(16) char smem_raw[MB * APAD * 4];   // 16.9 KB
    uint16_t* a_hi = (uint16_t*)smem_raw;            // [16][APAD]
    uint16_t* a_lo = a_hi + MB * APAD;
    float* outb = (float*)smem_raw;                  // reused: [16][OPAD]

    // stage + split rows (16*64 = 1024 float4, 4/thread)
    {
        const float4* src = (const float4*)(ctx + (size_t)row0 * Hq);
#pragma unroll
        for (int j = 0; j < 4; ++j) {
            int f = tid + j * 256;
            int r = f >> 6, cg = f & 63;
            float4 v = src[f];
            uint16_t h0 = f2bf(v.x), h1 = f2bf(v.y), h2 = f2bf(v.z), h3 = f2bf(v.w);
            ushort4 hh = {h0, h1, h2, h3};
            ushort4 ll = {f2bf(v.x - bf2f(h0)), f2bf(v.y - bf2f(h1)),
                          f2bf(v.z - bf2f(h2)), f2bf(v.w - bf2f(h3))};
            *(ushort4*)&a_hi[r * APAD + cg * 4] = hh;
            *(ushort4*)&a_lo[r * APAD + cg * 4] = ll;
        }
    }
    __syncthreads();

    int nt0 = w * 4;               // wave col-tile base
    int m = l & 15, quad = l >> 4;
    f32x4 acc[4];
#pragma unroll
    for (int t = 0; t < 4; ++t) acc[t] = (f32x4){0.f, 0.f, 0.f, 0.f};
#pragma unroll
    for (int kc = 0; kc < 8; ++kc) {
        short8 ah = *(const short8*)&a_hi[m * APAD + kc * 32 + quad * 8];
        short8 al = *(const short8*)&a_lo[m * APAD + kc * 32 + quad * 8];
#pragma unroll
        for (int t = 0; t < 4; ++t) {
            int fragi = (nt0 + t) * 8 + kc;
            short8 wh = *(const short8*)&wp_hi[fragi * 512 + l * 8];
            short8 wl = *(const short8*)&wp_lo[fragi * 512 + l * 8];
            acc[t] = __builtin_amdgcn_mfma_f32_16x16x32_bf16(ah, wh, acc[t], 0, 0, 0);
            acc[t] = __builtin_amdgcn_mfma_f32_16x16x32_bf16(ah, wl, acc[t], 0, 0, 0);
            acc[t] = __builtin_amdgcn_mfma_f32_16x16x32_bf16(al, wh, acc[t], 0, 0, 0);
        }
    }
    __syncthreads();   // all a_hi/a_lo reads done; reuse smem as outb

    // write C (+bias) to LDS staging (row=quad*4+r, col=(nt0+t)*16+m)
#pragma unroll
    for (int t = 0; t < 4; ++t) {
        int col = (nt0 + t) * 16 + m;
        float bv = bc[col];
#pragma unroll
        for (int r = 0; r < 4; ++r)
            outb[(quad * 4 + r) * OPAD + col] = acc[t][r] + bv;
    }
    __syncthreads();

    // uq / dsv: threads 0..127 -> (r, n)
    if (tid < MB * NHq) {
        int r = tid >> 3, n = tid & 7;
        float su = 0.f, sd = 0.f;
        for (int d = 0; d < Dq; ++d) {
            float v = outb[r * OPAD + n * Dq + d];
            su += v * upon[n * Dq + d];
            sd += v * down[n * Dq + d];
        }
        uq[(b * NHq + n) * Lq + l0 + r] = su;
        dsv[(b * NHq + n) * Lq + l0 + r] = sd;
    }
    // transposed store: thread tid owns channel tid, writes 16 l's
    {
        float* dst = ctx_hT + (size_t)(b * Hq + tid) * Lq + l0;
#pragma unroll
        for (int j = 0; j < MB / 4; ++j) {
            float4 o;
            o.x = outb[(4 * j + 0) * OPAD + tid];
            o.y = outb[(4 * j + 1) * OPAD + tid];
            o.z = outb[(4 * j + 2) * OPAD + tid];
            o.w = outb[(4 * j + 3) * OPAD + tid];
            ((float4*)dst)[j] = o;
        }
    }
}

// ---------------- attention: tiled (b, n, 64 l's) per block (unchanged R9) ----
__global__ void __launch_bounds__(256) k_attn(
        const float* __restrict__ ctx_hT, const float* __restrict__ types_h,
        const float* __restrict__ types_hT, const float* __restrict__ cross,
        const float* __restrict__ uq, const float* __restrict__ dsv,
        const float* __restrict__ dt, const unsigned char* __restrict__ maskp,
        float* __restrict__ update) {
    int blk = blockIdx.x;
    int lt = blk & 63, n = (blk >> 6) & 7, b = blk >> 9;
    int l0 = lt * TLq;
    int tid = threadIdx.x;
    int ls = tid >> 2;
    int q  = tid & 3;
    int pl = l0 + ls;
    bool mask_b8 = (maskp[1] != 0);

    __shared__ float chx_s[32 * 97];
    __shared__ float crs_s[32 * 36];
    __shared__ float cr_s[64 * 36];
    __shared__ float dots_s[64 * 19];
    __shared__ float tts_s[32 * 64];
    __shared__ float tts2_s[64 * 36 + 16];
    __shared__ float uqe[96], dsve[96], maskf[96], dts[64];

    {
        int d = tid >> 3, k = tid & 7;
        const float* grow = ctx_hT + ((size_t)(b * NHq + n) * Dq + d) * Lq;
        float* lrow = &chx_s[d * 97 + k * 12];
        if (l0 >= 16 && l0 <= Lq - 80) {
            const float4* g = (const float4*)(grow + (l0 - 16) + k * 12);
            float4 v0 = g[0], v1 = g[1], v2 = g[2];
            lrow[0] = v0.x; lrow[1] = v0.y; lrow[2]  = v0.z; lrow[3]  = v0.w;
            lrow[4] = v1.x; lrow[5] = v1.y; lrow[6]  = v1.z; lrow[7]  = v1.w;
            lrow[8] = v2.x; lrow[9] = v2.y; lrow[10] = v2.z; lrow[11] = v2.w;
        } else {
#pragma unroll
            for (int m = 0; m < 12; ++m) {
                int gl = l0 - 16 + k * 12 + m;
                int glw = (gl < 0) ? gl + Lq : ((gl >= Lq) ? gl - Lq : gl);
                lrow[m] = grow[glw];
            }
        }
    }
    {
        float4 v = ((const float4*)(cross + n * (Dq * Dq)))[tid];
        float* p = &crs_s[(tid >> 3) * 36 + (tid & 7) * 4];
        p[0] = v.x; p[1] = v.y; p[2] = v.z; p[3] = v.w;
    }
    {
        const float4* src = (const float4*)(types_hT + (size_t)(b * NHq + n) * Dq * Tq);
        float4* dst = (float4*)tts_s;
        dst[tid] = src[tid];
        dst[tid + 256] = src[tid + 256];
    }
    {
        int t = tid >> 2, c4 = tid & 3;
        const float4* src = (const float4*)(types_h + (size_t)(b * Tq + t) * Hq
                                            + n * Dq + 8 * c4);
        float* p = &tts2_s[t * 36 + 4 * (t >> 4) + 8 * c4];
        ((float4*)p)[0] = src[0];
        ((float4*)p)[1] = src[1];
    }
    if (tid < 96) {
        int gl = l0 - 16 + tid;
        int glw = (gl < 0) ? gl + Lq : ((gl >= Lq) ? gl - Lq : gl);
        uqe[tid] = uq[(b * NHq + n) * Lq + glw];
        unsigned char mb = mask_b8 ? maskp[b * Lq + glw]
                                   : maskp[(size_t)(b * Lq + glw) * 4];
        maskf[tid] = mb ? 1.f : 0.f;
    } else if (tid < 192) {
        int j = tid - 96;
        int gl = l0 - 16 + j;
        int glw = (gl < 0) ? gl + Lq : ((gl >= Lq) ? gl - Lq : gl);
        dsve[j] = dsv[(b * NHq + n) * Lq + glw];
    } else {
        dts[tid - 192] = dt[(b * NHq + n) * Tq + (tid - 192)];
    }
    __syncthreads();

    {
        float a[8];
#pragma unroll
        for (int ii = 0; ii < 8; ++ii) a[ii] = 0.f;
#pragma unroll 2
        for (int d = 0; d < Dq; ++d) {
            float chv = chx_s[d * 97 + ls + 16];
            const float4* cp = (const float4*)(&crs_s[d * 36 + 8 * q]);
            float4 c0 = cp[0], c1 = cp[1];
            a[0] = fmaf(chv, c0.x, a[0]); a[1] = fmaf(chv, c0.y, a[1]);
            a[2] = fmaf(chv, c0.z, a[2]); a[3] = fmaf(chv, c0.w, a[3]);
            a[4] = fmaf(chv, c1.x, a[4]); a[5] = fmaf(chv, c1.y, a[5]);
            a[6] = fmaf(chv, c1.z, a[6]); a[7] = fmaf(chv, c1.w, a[7]);
        }
        float4* wp = (float4*)(&cr_s[ls * 36 + 8 * q]);
        wp[0] = make_float4(a[0], a[1], a[2], a[3]);
        wp[1] = make_float4(a[4], a[5], a[6], a[7]);
    }

    float dot_self;
    {
        float cv8[8];
#pragma unroll
        for (int k = 0; k < 8; ++k) cv8[k] = cr_s[ls * 36 + 8 * q + k];
#pragma unroll
        for (int u = 0; u < 17; ++u) {
            float a = 0.f;
#pragma unroll
            for (int k = 0; k < 8; ++k)
                a = fmaf(cv8[k], chx_s[(8 * q + k) * 97 + ls + 16 + u], a);
            a += __shfl_xor(a, 1);
            a += __shfl_xor(a, 2);
            if (u == 0) dot_self = a;
            else if (q == 0) dots_s[ls * 19 + u] = a;
        }
    }

    float uq_l = uqe[ls + 16];
    float dsv_l = dsve[ls + 16];
    float cmask = maskf[ls + 16];

    int tb = 16 * q;
    float st[16];
#pragma unroll
    for (int j = 0; j < 16; ++j) st[j] = 0.f;
#pragma unroll 2
    for (int d = 0; d < Dq; ++d) {
        float cv = cr_s[ls * 36 + d];
        const float4* r4 = (const float4*)&tts_s[d * 64 + tb];
        float4 r0 = r4[0], r1 = r4[1], r2 = r4[2], r3 = r4[3];
        st[0]  = fmaf(cv, r0.x, st[0]);  st[1]  = fmaf(cv, r0.y, st[1]);
        st[2]  = fmaf(cv, r0.z, st[2]);  st[3]  = fmaf(cv, r0.w, st[3]);
        st[4]  = fmaf(cv, r1.x, st[4]);  st[5]  = fmaf(cv, r1.y, st[5]);
        st[6]  = fmaf(cv, r1.z, st[6]);  st[7]  = fmaf(cv, r1.w, st[7]);
        st[8]  = fmaf(cv, r2.x, st[8]);  st[9]  = fmaf(cv, r2.y, st[9]);
        st[10] = fmaf(cv, r2.z, st[10]); st[11] = fmaf(cv, r2.w, st[11]);
        st[12] = fmaf(cv, r3.x, st[12]); st[13] = fmaf(cv, r3.y, st[13]);
        st[14] = fmaf(cv, r3.z, st[14]); st[15] = fmaf(cv, r3.w, st[15]);
    }
#pragma unroll
    for (int j = 0; j < 16; ++j)
        st[j] = leaky(uq_l + dts[tb + j] + st[j]);

    int nv = (q == 0) ? 5 : 4;
    float su[4];
#pragma unroll
    for (int j = 0; j < 4; ++j) {
        int u = q + 1 + 4 * j;
        bool ok = (pl + u < Lq) && (maskf[ls + 16 + u] > 0.5f);
        su[j] = ok ? leaky(uqe[ls + 16 + u] + dsv_l + dots_s[ls * 19 + u])
                   : MASK_FILL;
    }

    float m = st[0];
#pragma unroll
    for (int j = 1; j < 16; ++j) m = fmaxf(m, st[j]);
#pragma unroll
    for (int j = 0; j < 5; ++j) {
        if (j < nv) {
            int v = q + 4 * j;
            if ((pl + v >= 16) && (cmask > 0.5f))
                m = fmaxf(m, leaky(uq_l + dsve[ls + v] + dot_self));
        }
    }
#pragma unroll
    for (int j = 0; j < 4; ++j) m = fmaxf(m, su[j]);
    m = fmaxf(m, __shfl_xor(m, 1));
    m = fmaxf(m, __shfl_xor(m, 2));
    float sum = 0.f, wself = 0.f;
#pragma unroll
    for (int j = 0; j < 16; ++j) { st[j] = __expf(st[j] - m); sum += st[j]; }
#pragma unroll
    for (int j = 0; j < 5; ++j) {
        if (j < nv) {
            int v = q + 4 * j;
            if ((pl + v >= 16) && (cmask > 0.5f)) {
                float e = __expf(leaky(uq_l + dsve[ls + v] + dot_self) - m);
                wself += e; sum += e;
            }
        }
    }
#pragma unroll
    for (int j = 0; j < 4; ++j)  { su[j] = __expf(su[j] - m); sum += su[j]; }
    sum += __shfl_xor(sum, 1);
    sum += __shfl_xor(sum, 2);
    float inv = 1.f / sum;
#pragma unroll
    for (int j = 0; j < 16; ++j) st[j] *= inv;
    wself *= inv;
#pragma unroll
    for (int j = 0; j < 4; ++j)  su[j] *= inv;

    float* dstrow = update + (size_t)(b * Lq + pl) * Hq + n * Dq;
#pragma unroll
    for (int c = 0; c < 4; ++c) {
        float u8[8];
#pragma unroll
        for (int e = 0; e < 8; ++e) u8[e] = 0.f;
#pragma unroll 2
        for (int j = 0; j < 16; ++j) {
            const float* vp = &tts2_s[(tb + j) * 36 + 4 * q + 8 * c];
            float4 a0 = ((const float4*)vp)[0];
            float4 a1 = ((const float4*)vp)[1];
            float wt = st[j];
            u8[0] = fmaf(wt, a0.x, u8[0]); u8[1] = fmaf(wt, a0.y, u8[1]);
            u8[2] = fmaf(wt, a0.z, u8[2]); u8[3] = fmaf(wt, a0.w, u8[3]);
            u8[4] = fmaf(wt, a1.x, u8[4]); u8[5] = fmaf(wt, a1.y, u8[5]);
            u8[6] = fmaf(wt, a1.z, u8[6]); u8[7] = fmaf(wt, a1.w, u8[7]);
        }
#pragma unroll
        for (int e = 0; e < 8; ++e)
            u8[e] = fmaf(wself, chx_s[(8 * c + e) * 97 + ls + 16], u8[e]);
#pragma unroll
        for (int j = 0; j < 4; ++j) {
            float wu = su[j];
            int u = q + 1 + 4 * j;
#pragma unroll
            for (int e = 0; e < 8; ++e)
                u8[e] = fmaf(wu, chx_s[(8 * c + e) * 97 + ls + 16 + u], u8[e]);
        }
#pragma unroll
        for (int e = 0; e < 8; ++e) {
            u8[e] += __shfl_xor(u8[e], 1);
            u8[e] += __shfl_xor(u8[e], 2);
        }
        if (q == c) {
            ((float4*)(dstrow + 8 * c))[0] = make_float4(u8[0], u8[1], u8[2], u8[3]);
            ((float4*)(dstrow + 8 * c))[1] = make_float4(u8[4], u8[5], u8[6], u8[7]);
        }
    }
}

// ---------------- output GEMM via MFMA + tanh ----------------
__global__ void __launch_bounds__(256) k_out(
        const float* __restrict__ update, const float* __restrict__ ctx,
        const uint16_t* __restrict__ wp_hi, const uint16_t* __restrict__ wp_lo,
        const float* __restrict__ bo, float* __restrict__ out) {
    int row0 = blockIdx.x * MB;
    int tid = threadIdx.x;
    int w = tid >> 6, l = tid & 63;
    __shared__ __align__(16) char smem_raw[MB * APAD * 4];
    uint16_t* a_hi = (uint16_t*)smem_raw;
    uint16_t* a_lo = a_hi + MB * APAD;

    {
        const float4* s0 = (const float4*)(update + (size_t)row0 * Hq);
        const float4* s1 = (const float4*)(ctx + (size_t)row0 * Hq);
#pragma unroll
        for (int j = 0; j < 4; ++j) {
            int f = tid + j * 256;
            int r = f >> 6, cg = f & 63;
            float4 a = s0[f], bv = s1[f];
            float4 v; v.x = a.x + bv.x; v.y = a.y + bv.y;
            v.z = a.z + bv.z; v.w = a.w + bv.w;
            uint16_t h0 = f2bf(v.x), h1 = f2bf(v.y), h2 = f2bf(v.z), h3 = f2bf(v.w);
            ushort4 hh = {h0, h1, h2, h3};
            ushort4 ll = {f2bf(v.x - bf2f(h0)), f2bf(v.y - bf2f(h1)),
                          f2bf(v.z - bf2f(h2)), f2bf(v.w - bf2f(h3))};
            *(ushort4*)&a_hi[r * APAD + cg * 4] = hh;
            *(ushort4*)&a_lo[r * APAD + cg * 4] = ll;
        }
    }
    __syncthreads();

    int nt0 = w * 4;
    int m = l & 15, quad = l >> 4;
    f32x4 acc[4];
#pragma unroll
    for (int t = 0; t < 4; ++t) acc[t] = (f32x4){0.f, 0.f, 0.f, 0.f};
#pragma unroll
    for (int kc = 0; kc < 8; ++kc) {
        short8 ah = *(const short8*)&a_hi[m * APAD + kc * 32 + quad * 8];
        short8 al = *(const short8*)&a_lo[m * APAD + kc * 32 + quad * 8];
#pragma unroll
        for (int t = 0; t < 4; ++t) {
            int fragi = (nt0 + t) * 8 + kc;
            short8 wh = *(const short8*)&wp_hi[fragi * 512 + l * 8];
            short8 wl = *(const short8*)&wp_lo[fragi * 512 + l * 8];
            acc[t] = __builtin_amdgcn_mfma_f32_16x16x32_bf16(ah, wh, acc[t], 0, 0, 0);
            acc[t] = __builtin_amdgcn_mfma_f32_16x16x32_bf16(ah, wl, acc[t], 0, 0, 0);
            acc[t] = __builtin_amdgcn_mfma_f32_16x16x32_bf16(al, wh, acc[t], 0, 0, 0);
        }
    }
    // epilogue: tanh + direct store (C layout: row=quad*4+r, col=16*(nt0+t)+m)
#pragma unroll
    for (int t = 0; t < 4; ++t) {
        int col = (nt0 + t) * 16 + m;
        float bv = bo[col];
#pragma unroll
        for (int r = 0; r < 4; ++r)
            out[(size_t)(row0 + quad * 4 + r) * Hq + col] = tanhf(acc[t][r] + bv);
    }
}

extern "C" void kernel_launch(void* const* d_in, const int* in_sizes, int n_in,
                              void* d_out, int out_size, void* d_ws, size_t ws_size,
                              hipStream_t stream) {
    const float* context   = (const float*)d_in[0];
    const float* types     = (const float*)d_in[1];
    const unsigned char* cmask = (const unsigned char*)d_in[2];
    const float* W_types   = (const float*)d_in[3];
    const float* b_types   = (const float*)d_in[4];
    const float* W_context = (const float*)d_in[5];
    const float* b_context = (const float*)d_in[6];
    const float* upon      = (const float*)d_in[7];
    const float* down      = (const float*)d_in[8];
    const float* cross     = (const float*)d_in[9];
    const float* W_out     = (const float*)d_in[10];
    const float* b_out     = (const float*)d_in[11];
    float* out = (float*)d_out;
    float* ws  = (float*)d_ws;

    // ws: ctx_hT (16MB) + update (16MB) + W packs (512 KB) = 33.05 MB
    float* ctx_hT   = ws;             // [b][n][d][l]
    float* update   = ws + 4194304;
    uint16_t* wcp_hi = (uint16_t*)(ws + 8388608);
    uint16_t* wcp_lo = wcp_hi + 65536;
    uint16_t* wop_hi = wcp_hi + 131072;
    uint16_t* wop_lo = wcp_hi + 196608;

    // Small intermediates in d_out scratch (k_out overwrites all of d_out last).
    float* types_h  = out;            // 65536   [b][t][h]
    float* types_hT = out + 65536;    // 65536   [b][n][d][t]
    float* down_t   = out + 131072;   // 2048
    float* uqp      = out + 133120;   // 131072
    float* dsvp     = out + 264192;   // 131072

    k_prep<<<128 + Bq * Tq, 256, 0, stream>>>(W_context, W_out,
                                              wcp_hi, wcp_lo, wop_hi, wop_lo,
                                              types, W_types, b_types, down,
                                              types_h, types_hT, down_t);
    k_ctx<<<Bq * Lq / MB, 256, 0, stream>>>(context, wcp_hi, wcp_lo, b_context,
                                            upon, down, ctx_hT, uqp, dsvp);
    k_attn<<<Bq * NHq * (Lq / TLq), 256, 0, stream>>>(ctx_hT, types_h, types_hT, cross,
                                                      uqp, dsvp, down_t, cmask, update);
    k_out<<<Bq * Lq / MB, 256, 0, stream>>>(update, context, wop_hi, wop_lo, b_out, out);
}